// Round 4
// baseline (1305.153 us; speedup 1.0000x reference)
//
#include <hip/hip_runtime.h>
#include <hip/hip_bf16.h>

static constexpr int N_NODES = 100000;
static constexpr int N_EDGES = 3200000;
static constexpr int IN_CH = 512;
static constexpr int H = 16;
static constexpr int TB = 256;

static constexpr int BN = 64;                        // nodes per bucket
static constexpr int NB = (N_NODES + BN - 1) / BN;   // 1563 buckets
static constexpr int NSEG = 8;                       // segments ~ XCDs (blockIdx%8)
static constexpr int PAD = 4;                        // ints per counter (16B) to spread atomic lines
static constexpr int GSCAT = 1024;                   // WGs for hist2/bscatter (must match!)

__global__ void k_zero(int* __restrict__ p, int n) {
  int i = blockIdx.x * blockDim.x + threadIdx.x;
  if (i < n) p[i] = 0;
}

// 2-D histogram: cnt2[seg][bucket]; seg = blockIdx%8 (XCD heuristic).
// Edge->seg mapping MUST be identical to k_bscatter (same grid GSCAT).
__global__ void k_hist2(const int* __restrict__ ei, int* __restrict__ cnt2) {
  int seg = blockIdx.x & 7;
  int idx = blockIdx.x * TB + threadIdx.x;
  for (int e = idx; e < N_EDGES; e += GSCAT * TB) {
    int d = ei[N_EDGES + e];
    atomicAdd(&cnt2[(seg * NB + (d >> 6)) * PAD], 1);
  }
}

// Single-WG hierarchical scan: bucket totals -> base[] (bucket-contiguous regions),
// and cursor init cur2[seg][b] = base[b] + prefix over segs.
__global__ void k_scan(const int* __restrict__ cnt2, int* __restrict__ cur2,
                       int* __restrict__ base) {
  __shared__ int lds[TB];
  int t = threadIdx.x;
  const int C = 7;  // 256*7 = 1792 >= NB
  int tot[C];
  int tsum = 0;
#pragma unroll
  for (int j = 0; j < C; j++) {
    int b = t * C + j;
    int s = 0;
    if (b < NB) {
#pragma unroll
      for (int k = 0; k < NSEG; k++) s += cnt2[(k * NB + b) * PAD];
    }
    tot[j] = s;
    tsum += s;
  }
  lds[t] = tsum;
  __syncthreads();
  for (int off = 1; off < TB; off <<= 1) {
    int x = (t >= off) ? lds[t - off] : 0;
    __syncthreads();
    lds[t] += x;
    __syncthreads();
  }
  int run = (t == 0) ? 0 : lds[t - 1];
#pragma unroll
  for (int j = 0; j < C; j++) {
    int b = t * C + j;
    if (b < NB) {
      base[b] = run;
      int c = run;
#pragma unroll
      for (int k = 0; k < NSEG; k++) {
        cur2[(k * NB + b) * PAD] = c;
        c += cnt2[(k * NB + b) * PAD];
      }
      run += tot[j];
    }
  }
  if (t == TB - 1) base[NB] = lds[TB - 1];
}

// Scatter packed edges into per-(seg,bucket) contiguous sub-regions.
// pack = (dst&63)<<17 | src   (src < 2^17)
__global__ void k_bscatter(const int* __restrict__ ei, int* __restrict__ cur2,
                           int* __restrict__ ebuf) {
  int seg = blockIdx.x & 7;
  int idx = blockIdx.x * TB + threadIdx.x;
  for (int e = idx; e < N_EDGES; e += GSCAT * TB) {
    int s = ei[e];
    int d = ei[N_EDGES + e];
    int slot = atomicAdd(&cur2[(seg * NB + (d >> 6)) * PAD], 1);
    ebuf[slot] = ((d & 63) << 17) | s;
  }
}

// Per-bucket degree count -> disq = 1/sqrt(deg+1)
__global__ void k_bdeg(const int* __restrict__ base, const int* __restrict__ ebuf,
                       float* __restrict__ disq) {
  __shared__ int cnt[BN];
  int b = blockIdx.x, t = threadIdx.x;
  if (t < BN) cnt[t] = 0;
  __syncthreads();
  int beg = base[b], end = base[b + 1];
  for (int j = beg + t; j < end; j += TB) atomicAdd(&cnt[ebuf[j] >> 17], 1);
  __syncthreads();
  int node = b * BN + t;
  if (t < BN && node < N_NODES) disq[node] = 1.0f / sqrtf((float)cnt[t] + 1.0f);
}

// h = X (N x 512) @ W (512 x 16). Thread per row; W wave-uniform -> scalar loads.
__global__ void k_gemm1(const float* __restrict__ x, const float* __restrict__ W,
                        float* __restrict__ h) {
  int r = blockIdx.x * blockDim.x + threadIdx.x;
  if (r >= N_NODES) return;
  const float4* xr = (const float4*)(x + (size_t)r * IN_CH);
  float acc[H];
#pragma unroll
  for (int c = 0; c < H; c++) acc[c] = 0.f;
  for (int k4 = 0; k4 < IN_CH / 4; k4++) {
    float4 xv = xr[k4];
    const float* wr = W + k4 * 4 * H;
    float xs[4] = {xv.x, xv.y, xv.z, xv.w};
#pragma unroll
    for (int j = 0; j < 4; j++) {
#pragma unroll
      for (int c = 0; c < H; c++) acc[c] = fmaf(xs[j], wr[j * H + c], acc[c]);
    }
  }
  float4* hp = (float4*)(h + (size_t)r * H);
  hp[0] = make_float4(acc[0], acc[1], acc[2], acc[3]);
  hp[1] = make_float4(acc[4], acc[5], acc[6], acc[7]);
  hp[2] = make_float4(acc[8], acc[9], acc[10], acc[11]);
  hp[3] = make_float4(acc[12], acc[13], acc[14], acc[15]);
}

// Bucket aggregation, 16 channels: one WG per bucket, LDS acc[64][16].
// agg[node] = (sum_e h[src]*disq[src]) * dn + h[node]*dn^2 + bias
__global__ void k_bagg(const int* __restrict__ base, const int* __restrict__ ebuf,
                       const float* __restrict__ disq, const float* __restrict__ h,
                       const float* __restrict__ bias, float* __restrict__ agg) {
  __shared__ float acc[BN * H];  // 4 KB
  int b = blockIdx.x, t = threadIdx.x;
  for (int i = t; i < BN * H; i += TB) acc[i] = 0.f;
  __syncthreads();
  int beg = base[b], end = base[b + 1];
  int grp = t >> 4, lane = t & 15;  // 16 groups x 16 lanes; group per edge
  for (int j = beg + grp; j < end; j += 16) {
    int p = ebuf[j];
    int src = p & 0x1FFFF;
    int ld = p >> 17;
    float v = h[(size_t)src * H + lane] * disq[src];
    atomicAdd(&acc[ld * H + lane], v);
  }
  __syncthreads();
  int nl = t >> 2, q = t & 3;
  int node = b * BN + nl;
  if (node < N_NODES) {
    float dn = disq[node];
    float dn2 = dn * dn;
    const float4 hv = *(const float4*)(h + (size_t)node * H + q * 4);
    const float4 bv = *(const float4*)(bias + q * 4);
    const float* a = acc + nl * H + q * 4;
    float4 r;
    r.x = fmaf(a[0], dn, fmaf(hv.x, dn2, bv.x));
    r.y = fmaf(a[1], dn, fmaf(hv.y, dn2, bv.y));
    r.z = fmaf(a[2], dn, fmaf(hv.z, dn2, bv.z));
    r.w = fmaf(a[3], dn, fmaf(hv.w, dn2, bv.w));
    *(float4*)(agg + (size_t)node * H + q * 4) = r;
  }
}

// h = relu(agg) @ W (16x16); relu fused on load
__global__ void k_gemm16(const float* __restrict__ agg, const float* __restrict__ W,
                         float* __restrict__ h) {
  int r = blockIdx.x * blockDim.x + threadIdx.x;
  if (r >= N_NODES) return;
  const float4* ap = (const float4*)(agg + (size_t)r * H);
  float v[H];
#pragma unroll
  for (int q = 0; q < 4; q++) {
    float4 t = ap[q];
    v[4 * q + 0] = fmaxf(t.x, 0.f);
    v[4 * q + 1] = fmaxf(t.y, 0.f);
    v[4 * q + 2] = fmaxf(t.z, 0.f);
    v[4 * q + 3] = fmaxf(t.w, 0.f);
  }
  float acc[H];
#pragma unroll
  for (int c = 0; c < H; c++) acc[c] = 0.f;
#pragma unroll
  for (int k = 0; k < H; k++) {
#pragma unroll
    for (int c = 0; c < H; c++) acc[c] = fmaf(v[k], W[k * H + c], acc[c]);
  }
  float4* hp = (float4*)(h + (size_t)r * H);
  hp[0] = make_float4(acc[0], acc[1], acc[2], acc[3]);
  hp[1] = make_float4(acc[4], acc[5], acc[6], acc[7]);
  hp[2] = make_float4(acc[8], acc[9], acc[10], acc[11]);
  hp[3] = make_float4(acc[12], acc[13], acc[14], acc[15]);
}

// h3 = relu(agg2) @ W3 (16x1)
__global__ void k_gemm_last(const float* __restrict__ agg, const float* __restrict__ W,
                            float* __restrict__ h3) {
  int r = blockIdx.x * blockDim.x + threadIdx.x;
  if (r >= N_NODES) return;
  const float4* ap = (const float4*)(agg + (size_t)r * H);
  float acc = 0.f;
#pragma unroll
  for (int q = 0; q < 4; q++) {
    float4 t = ap[q];
    acc = fmaf(fmaxf(t.x, 0.f), W[4 * q + 0], acc);
    acc = fmaf(fmaxf(t.y, 0.f), W[4 * q + 1], acc);
    acc = fmaf(fmaxf(t.z, 0.f), W[4 * q + 2], acc);
    acc = fmaf(fmaxf(t.w, 0.f), W[4 * q + 3], acc);
  }
  h3[r] = acc;
}

// Bucket aggregation, 1 channel: thread per edge, LDS acc[64].
__global__ void k_bagg1(const int* __restrict__ base, const int* __restrict__ ebuf,
                        const float* __restrict__ disq, const float* __restrict__ h3,
                        const float* __restrict__ bias, float* __restrict__ out) {
  __shared__ float acc[BN];
  int b = blockIdx.x, t = threadIdx.x;
  if (t < BN) acc[t] = 0.f;
  __syncthreads();
  int beg = base[b], end = base[b + 1];
  for (int j = beg + t; j < end; j += TB) {
    int p = ebuf[j];
    int src = p & 0x1FFFF;
    atomicAdd(&acc[p >> 17], h3[src] * disq[src]);
  }
  __syncthreads();
  int node = b * BN + t;
  if (t < BN && node < N_NODES) {
    float dn = disq[node];
    out[node] = fmaf(acc[t], dn, fmaf(h3[node] * dn, dn, bias[0]));
  }
}

extern "C" void kernel_launch(void* const* d_in, const int* in_sizes, int n_in,
                              void* d_out, int out_size, void* d_ws, size_t ws_size,
                              hipStream_t stream) {
  const float* x = (const float*)d_in[0];
  const int* ei = (const int*)d_in[1];  // integer inputs delivered as int32
  const float* W1 = (const float*)d_in[2];
  const float* b1 = (const float*)d_in[3];
  const float* W2 = (const float*)d_in[4];
  const float* b2 = (const float*)d_in[5];
  const float* W3 = (const float*)d_in[6];
  const float* b3 = (const float*)d_in[7];
  float* out = (float*)d_out;

  // Workspace (~26.2 MB):
  int* cnt2 = (int*)d_ws;                      // NSEG*NB*PAD = 50016
  int* cur2 = cnt2 + NSEG * NB * PAD;          // 50016
  int* base = cur2 + NSEG * NB * PAD;          // NB+1
  int* ebuf = base + (NB + 1);                 // E packed edges
  float* disq = (float*)(ebuf + N_EDGES);      // N
  float* h = disq + N_NODES;                   // 16N
  float* agg = h + (size_t)N_NODES * H;        // 16N
  float* h3 = h;                               // reuse (h2 dead after agg2)

  int gN = (N_NODES + TB - 1) / TB;

  // Build bucketed edge buffer
  int nCnt = NSEG * NB * PAD;
  k_zero<<<(nCnt + TB - 1) / TB, TB, 0, stream>>>(cnt2, nCnt);
  k_hist2<<<GSCAT, TB, 0, stream>>>(ei, cnt2);
  k_scan<<<1, TB, 0, stream>>>(cnt2, cur2, base);
  k_bscatter<<<GSCAT, TB, 0, stream>>>(ei, cur2, ebuf);
  k_bdeg<<<NB, TB, 0, stream>>>(base, ebuf, disq);

  // Layer 1
  k_gemm1<<<gN, TB, 0, stream>>>(x, W1, h);
  k_bagg<<<NB, TB, 0, stream>>>(base, ebuf, disq, h, b1, agg);
  // Layer 2
  k_gemm16<<<gN, TB, 0, stream>>>(agg, W2, h);
  k_bagg<<<NB, TB, 0, stream>>>(base, ebuf, disq, h, b2, agg);
  // Layer 3
  k_gemm_last<<<gN, TB, 0, stream>>>(agg, W3, h3);
  k_bagg1<<<NB, TB, 0, stream>>>(base, ebuf, disq, h3, b3, out);
}

// Round 5
// 1206.141 us; speedup vs baseline: 1.0821x; 1.0821x over previous
//
#include <hip/hip_runtime.h>
#include <hip/hip_bf16.h>

static constexpr int N_NODES = 100000;
static constexpr int N_EDGES = 3200000;
static constexpr int IN_CH = 512;
static constexpr int H = 16;
static constexpr int TB = 256;

static constexpr int BN = 64;                        // nodes per bucket
static constexpr int NB = (N_NODES + BN - 1) / BN;   // 1563 buckets
static constexpr int NSEG = 8;                       // segments ~ XCDs (blockIdx%8)
static constexpr int PAD = 4;                        // ints per counter (16B)
static constexpr int GSCAT = 1024;                   // WGs for hist2/bscatter (must match!)

__global__ void k_zero(int* __restrict__ p, int n) {
  int i = blockIdx.x * blockDim.x + threadIdx.x;
  if (i < n) p[i] = 0;
}

// 2-D histogram: cnt2[seg][bucket]; seg = blockIdx%8 (XCD heuristic).
__global__ void k_hist2(const int* __restrict__ ei, int* __restrict__ cnt2) {
  int seg = blockIdx.x & 7;
  int idx = blockIdx.x * TB + threadIdx.x;
  for (int e = idx; e < N_EDGES; e += GSCAT * TB) {
    int d = ei[N_EDGES + e];
    atomicAdd(&cnt2[(seg * NB + (d >> 6)) * PAD], 1);
  }
}

// Single-WG hierarchical scan: bucket totals -> base[]; cursors cur2[seg][b].
__global__ void k_scan(const int* __restrict__ cnt2, int* __restrict__ cur2,
                       int* __restrict__ base) {
  __shared__ int lds[TB];
  int t = threadIdx.x;
  const int C = 7;  // 256*7 = 1792 >= NB
  int tot[C];
  int tsum = 0;
#pragma unroll
  for (int j = 0; j < C; j++) {
    int b = t * C + j;
    int s = 0;
    if (b < NB) {
#pragma unroll
      for (int k = 0; k < NSEG; k++) s += cnt2[(k * NB + b) * PAD];
    }
    tot[j] = s;
    tsum += s;
  }
  lds[t] = tsum;
  __syncthreads();
  for (int off = 1; off < TB; off <<= 1) {
    int x = (t >= off) ? lds[t - off] : 0;
    __syncthreads();
    lds[t] += x;
    __syncthreads();
  }
  int run = (t == 0) ? 0 : lds[t - 1];
#pragma unroll
  for (int j = 0; j < C; j++) {
    int b = t * C + j;
    if (b < NB) {
      base[b] = run;
      int c = run;
#pragma unroll
      for (int k = 0; k < NSEG; k++) {
        cur2[(k * NB + b) * PAD] = c;
        c += cnt2[(k * NB + b) * PAD];
      }
      run += tot[j];
    }
  }
  if (t == TB - 1) base[NB] = lds[TB - 1];
}

// Scatter packed edges into per-(seg,bucket) contiguous sub-regions.
// pack = (dst&63)<<17 | src   (src < 2^17)
__global__ void k_bscatter(const int* __restrict__ ei, int* __restrict__ cur2,
                           int* __restrict__ ebuf) {
  int seg = blockIdx.x & 7;
  int idx = blockIdx.x * TB + threadIdx.x;
  for (int e = idx; e < N_EDGES; e += GSCAT * TB) {
    int s = ei[e];
    int d = ei[N_EDGES + e];
    int slot = atomicAdd(&cur2[(seg * NB + (d >> 6)) * PAD], 1);
    ebuf[slot] = ((d & 63) << 17) | s;
  }
}

// Per-bucket degree count -> disq = 1/sqrt(deg+1)
__global__ void k_bdeg(const int* __restrict__ base, const int* __restrict__ ebuf,
                       float* __restrict__ disq) {
  __shared__ int cnt[BN];
  int b = blockIdx.x, t = threadIdx.x;
  if (t < BN) cnt[t] = 0;
  __syncthreads();
  int beg = base[b], end = base[b + 1];
  for (int j = beg + t; j < end; j += TB) atomicAdd(&cnt[ebuf[j] >> 17], 1);
  __syncthreads();
  int node = b * BN + t;
  if (t < BN && node < N_NODES) disq[node] = 1.0f / sqrtf((float)cnt[t] + 1.0f);
}

// hs = (X @ W1) * disq[row], written as two half-tables [N][8] (3.2 MB each).
__global__ void k_gemm1(const float* __restrict__ x, const float* __restrict__ W,
                        const float* __restrict__ disq,
                        float* __restrict__ hlo, float* __restrict__ hhi) {
  int r = blockIdx.x * blockDim.x + threadIdx.x;
  if (r >= N_NODES) return;
  const float4* xr = (const float4*)(x + (size_t)r * IN_CH);
  float acc[H];
#pragma unroll
  for (int c = 0; c < H; c++) acc[c] = 0.f;
  for (int k4 = 0; k4 < IN_CH / 4; k4++) {
    float4 xv = xr[k4];
    const float* wr = W + k4 * 4 * H;
    float xs[4] = {xv.x, xv.y, xv.z, xv.w};
#pragma unroll
    for (int j = 0; j < 4; j++) {
#pragma unroll
      for (int c = 0; c < H; c++) acc[c] = fmaf(xs[j], wr[j * H + c], acc[c]);
    }
  }
  float dn = disq[r];
  float4* lo = (float4*)(hlo + (size_t)r * 8);
  float4* hi = (float4*)(hhi + (size_t)r * 8);
  lo[0] = make_float4(acc[0] * dn, acc[1] * dn, acc[2] * dn, acc[3] * dn);
  lo[1] = make_float4(acc[4] * dn, acc[5] * dn, acc[6] * dn, acc[7] * dn);
  hi[0] = make_float4(acc[8] * dn, acc[9] * dn, acc[10] * dn, acc[11] * dn);
  hi[1] = make_float4(acc[12] * dn, acc[13] * dn, acc[14] * dn, acc[15] * dn);
}

// Half-channel bucket aggregation: grid (NB, 2). Table per half = 3.2 MB (L2-resident).
// agg[n][half*8+c] = dn*(sum_e hs[src][c] + hs[n][c]) + b[half*8+c]
__global__ void k_bagg(const int* __restrict__ base, const int* __restrict__ ebuf,
                       const float* __restrict__ disq,
                       const float* __restrict__ hlo, const float* __restrict__ hhi,
                       const float* __restrict__ bias, float* __restrict__ agg) {
  __shared__ float acc[BN * 8];  // 2 KB
  int b = blockIdx.x, half = blockIdx.y, t = threadIdx.x;
  const float* hs = half ? hhi : hlo;
  for (int i = t; i < BN * 8; i += TB) acc[i] = 0.f;
  __syncthreads();
  int beg = base[b], end = base[b + 1];
  int grp = t >> 3, lane = t & 7;  // 32 groups x 8 lanes; group per edge
  for (int j = beg + grp; j < end; j += 32) {
    int p = ebuf[j];
    int src = p & 0x1FFFF;
    int ld = p >> 17;
    atomicAdd(&acc[ld * 8 + lane], hs[(size_t)src * 8 + lane]);
  }
  __syncthreads();
  if (t < 128) {
    int nl = t >> 1, q = t & 1;
    int node = b * BN + nl;
    if (node < N_NODES) {
      float dn = disq[node];
      const float4 hv = *(const float4*)(hs + (size_t)node * 8 + q * 4);
      const float4 bv = *(const float4*)(bias + half * 8 + q * 4);
      const float* a = acc + nl * 8 + q * 4;
      float4 r;
      r.x = fmaf(a[0] + hv.x, dn, bv.x);
      r.y = fmaf(a[1] + hv.y, dn, bv.y);
      r.z = fmaf(a[2] + hv.z, dn, bv.z);
      r.w = fmaf(a[3] + hv.w, dn, bv.w);
      *(float4*)(agg + (size_t)node * H + half * 8 + q * 4) = r;
    }
  }
}

// hs = (relu(agg) @ W2) * disq, written as halves
__global__ void k_gemm16(const float* __restrict__ agg, const float* __restrict__ W,
                         const float* __restrict__ disq,
                         float* __restrict__ hlo, float* __restrict__ hhi) {
  int r = blockIdx.x * blockDim.x + threadIdx.x;
  if (r >= N_NODES) return;
  const float4* ap = (const float4*)(agg + (size_t)r * H);
  float v[H];
#pragma unroll
  for (int q = 0; q < 4; q++) {
    float4 t = ap[q];
    v[4 * q + 0] = fmaxf(t.x, 0.f);
    v[4 * q + 1] = fmaxf(t.y, 0.f);
    v[4 * q + 2] = fmaxf(t.z, 0.f);
    v[4 * q + 3] = fmaxf(t.w, 0.f);
  }
  float acc[H];
#pragma unroll
  for (int c = 0; c < H; c++) acc[c] = 0.f;
#pragma unroll
  for (int k = 0; k < H; k++) {
#pragma unroll
    for (int c = 0; c < H; c++) acc[c] = fmaf(v[k], W[k * H + c], acc[c]);
  }
  float dn = disq[r];
  float4* lo = (float4*)(hlo + (size_t)r * 8);
  float4* hi = (float4*)(hhi + (size_t)r * 8);
  lo[0] = make_float4(acc[0] * dn, acc[1] * dn, acc[2] * dn, acc[3] * dn);
  lo[1] = make_float4(acc[4] * dn, acc[5] * dn, acc[6] * dn, acc[7] * dn);
  hi[0] = make_float4(acc[8] * dn, acc[9] * dn, acc[10] * dn, acc[11] * dn);
  hi[1] = make_float4(acc[12] * dn, acc[13] * dn, acc[14] * dn, acc[15] * dn);
}

// hs3 = (relu(agg2) @ W3) * disq   (400 KB table)
__global__ void k_gemm_last(const float* __restrict__ agg, const float* __restrict__ W,
                            const float* __restrict__ disq, float* __restrict__ hs3) {
  int r = blockIdx.x * blockDim.x + threadIdx.x;
  if (r >= N_NODES) return;
  const float4* ap = (const float4*)(agg + (size_t)r * H);
  float acc = 0.f;
#pragma unroll
  for (int q = 0; q < 4; q++) {
    float4 t = ap[q];
    acc = fmaf(fmaxf(t.x, 0.f), W[4 * q + 0], acc);
    acc = fmaf(fmaxf(t.y, 0.f), W[4 * q + 1], acc);
    acc = fmaf(fmaxf(t.z, 0.f), W[4 * q + 2], acc);
    acc = fmaf(fmaxf(t.w, 0.f), W[4 * q + 3], acc);
  }
  hs3[r] = acc * disq[r];
}

// 1-channel bucket aggregation: out[n] = dn*(sum_e hs3[src] + hs3[n]) + b3
__global__ void k_bagg1(const int* __restrict__ base, const int* __restrict__ ebuf,
                        const float* __restrict__ disq, const float* __restrict__ hs3,
                        const float* __restrict__ bias, float* __restrict__ out) {
  __shared__ float acc[BN];
  int b = blockIdx.x, t = threadIdx.x;
  if (t < BN) acc[t] = 0.f;
  __syncthreads();
  int beg = base[b], end = base[b + 1];
  for (int j = beg + t; j < end; j += TB) {
    int p = ebuf[j];
    atomicAdd(&acc[p >> 17], hs3[p & 0x1FFFF]);
  }
  __syncthreads();
  int node = b * BN + t;
  if (t < BN && node < N_NODES) {
    out[node] = fmaf(acc[t] + hs3[node], disq[node], bias[0]);
  }
}

extern "C" void kernel_launch(void* const* d_in, const int* in_sizes, int n_in,
                              void* d_out, int out_size, void* d_ws, size_t ws_size,
                              hipStream_t stream) {
  const float* x = (const float*)d_in[0];
  const int* ei = (const int*)d_in[1];  // integer inputs delivered as int32
  const float* W1 = (const float*)d_in[2];
  const float* b1 = (const float*)d_in[3];
  const float* W2 = (const float*)d_in[4];
  const float* b2 = (const float*)d_in[5];
  const float* W3 = (const float*)d_in[6];
  const float* b3 = (const float*)d_in[7];
  float* out = (float*)d_out;

  // Workspace (~26.4 MB):
  int* cnt2 = (int*)d_ws;                      // NSEG*NB*PAD
  int* cur2 = cnt2 + NSEG * NB * PAD;          // NSEG*NB*PAD
  int* base = cur2 + NSEG * NB * PAD;          // NB+1
  int* ebuf = base + (NB + 1);                 // E packed edges
  float* disq = (float*)(ebuf + N_EDGES);      // N
  float* hlo = disq + N_NODES;                 // 8N (3.2 MB)
  float* hhi = hlo + (size_t)N_NODES * 8;      // 8N (3.2 MB)
  float* agg = hhi + (size_t)N_NODES * 8;      // 16N
  float* hs3 = hlo;                            // reuse (hlo dead after layer-2 bagg)

  int gN = (N_NODES + TB - 1) / TB;

  // Build bucketed edge buffer + degrees
  int nCnt = NSEG * NB * PAD;
  k_zero<<<(nCnt + TB - 1) / TB, TB, 0, stream>>>(cnt2, nCnt);
  k_hist2<<<GSCAT, TB, 0, stream>>>(ei, cnt2);
  k_scan<<<1, TB, 0, stream>>>(cnt2, cur2, base);
  k_bscatter<<<GSCAT, TB, 0, stream>>>(ei, cur2, ebuf);
  k_bdeg<<<NB, TB, 0, stream>>>(base, ebuf, disq);

  // Layer 1
  k_gemm1<<<gN, TB, 0, stream>>>(x, W1, disq, hlo, hhi);
  k_bagg<<<dim3(NB, 2), TB, 0, stream>>>(base, ebuf, disq, hlo, hhi, b1, agg);
  // Layer 2
  k_gemm16<<<gN, TB, 0, stream>>>(agg, W2, disq, hlo, hhi);
  k_bagg<<<dim3(NB, 2), TB, 0, stream>>>(base, ebuf, disq, hlo, hhi, b2, agg);
  // Layer 3
  k_gemm_last<<<gN, TB, 0, stream>>>(agg, W3, disq, hs3);
  k_bagg1<<<NB, TB, 0, stream>>>(base, ebuf, disq, hs3, b3, out);
}

// Round 6
// 874.331 us; speedup vs baseline: 1.4927x; 1.3795x over previous
//
#include <hip/hip_runtime.h>
#include <hip/hip_bf16.h>

static constexpr int N_NODES = 100000;
static constexpr int N_EDGES = 3200000;
static constexpr int IN_CH = 512;
static constexpr int H = 16;
static constexpr int TB = 256;

static constexpr int BN = 64;                        // nodes per bucket
static constexpr int NB = (N_NODES + BN - 1) / BN;   // 1563 buckets
static constexpr int NSEG = 8;                       // segments ~ XCDs (blockIdx%8)
static constexpr int PAD = 4;                        // ints per counter (16B)
static constexpr int GSCAT = 1024;                   // WGs for hist2/bscatter (must match!)

__global__ void k_zero(int* __restrict__ p, int n) {
  int i = blockIdx.x * blockDim.x + threadIdx.x;
  if (i < n) p[i] = 0;
}

// 2-D histogram: cnt2[seg][bucket]; seg = blockIdx%8 (XCD heuristic).
__global__ void k_hist2(const int* __restrict__ ei, int* __restrict__ cnt2) {
  int seg = blockIdx.x & 7;
  int idx = blockIdx.x * TB + threadIdx.x;
  for (int e = idx; e < N_EDGES; e += GSCAT * TB) {
    int d = ei[N_EDGES + e];
    atomicAdd(&cnt2[(seg * NB + (d >> 6)) * PAD], 1);
  }
}

// Single-WG hierarchical scan: bucket totals -> base[]; cursors cur2[seg][b].
__global__ void k_scan(const int* __restrict__ cnt2, int* __restrict__ cur2,
                       int* __restrict__ base) {
  __shared__ int lds[TB];
  int t = threadIdx.x;
  const int C = 7;  // 256*7 = 1792 >= NB
  int tot[C];
  int tsum = 0;
#pragma unroll
  for (int j = 0; j < C; j++) {
    int b = t * C + j;
    int s = 0;
    if (b < NB) {
#pragma unroll
      for (int k = 0; k < NSEG; k++) s += cnt2[(k * NB + b) * PAD];
    }
    tot[j] = s;
    tsum += s;
  }
  lds[t] = tsum;
  __syncthreads();
  for (int off = 1; off < TB; off <<= 1) {
    int x = (t >= off) ? lds[t - off] : 0;
    __syncthreads();
    lds[t] += x;
    __syncthreads();
  }
  int run = (t == 0) ? 0 : lds[t - 1];
#pragma unroll
  for (int j = 0; j < C; j++) {
    int b = t * C + j;
    if (b < NB) {
      base[b] = run;
      int c = run;
#pragma unroll
      for (int k = 0; k < NSEG; k++) {
        cur2[(k * NB + b) * PAD] = c;
        c += cnt2[(k * NB + b) * PAD];
      }
      run += tot[j];
    }
  }
  if (t == TB - 1) base[NB] = lds[TB - 1];
}

// Scatter packed edges into per-(seg,bucket) contiguous sub-regions.
// pack = (dst&63)<<17 | src   (src < 2^17)
__global__ void k_bscatter(const int* __restrict__ ei, int* __restrict__ cur2,
                           int* __restrict__ ebuf) {
  int seg = blockIdx.x & 7;
  int idx = blockIdx.x * TB + threadIdx.x;
  for (int e = idx; e < N_EDGES; e += GSCAT * TB) {
    int s = ei[e];
    int d = ei[N_EDGES + e];
    int slot = atomicAdd(&cur2[(seg * NB + (d >> 6)) * PAD], 1);
    ebuf[slot] = ((d & 63) << 17) | s;
  }
}

// Per-bucket counting sort by local dst: ebuf (packed) -> ebuf2 (plain src,
// grouped by node). Also emits nrs[] boundaries and disq[].
// One WG per bucket; all writes to this bucket's region come from one CU, so
// its XCD L2 merges lines (no write amplification).
__global__ void k_bsort(const int* __restrict__ base, const int* __restrict__ ebuf,
                        int* __restrict__ ebuf2, int* __restrict__ nrs,
                        float* __restrict__ disq) {
  __shared__ int cnt[BN];
  __shared__ int cur[BN];
  int b = blockIdx.x, t = threadIdx.x;
  if (t < BN) cnt[t] = 0;
  __syncthreads();
  int beg = base[b], end = base[b + 1];
  // pass 1: per-node degree
  for (int j = beg + t; j < end; j += TB) atomicAdd(&cnt[ebuf[j] >> 17], 1);
  __syncthreads();
  if (t == 0) {
    int run = beg;
    for (int i = 0; i < BN; i++) { cur[i] = run; run += cnt[i]; }
  }
  __syncthreads();
  int mycur = (t < BN) ? cur[t] : 0;   // snapshot before pass-2 mutates cur
  int mycnt = (t < BN) ? cnt[t] : 0;
  __syncthreads();
  if (t < BN) {
    int node = b * BN + t;
    if (node <= N_NODES) nrs[node] = mycur;       // node==N writes final bound E
    if (node < N_NODES) disq[node] = 1.0f / sqrtf((float)mycnt + 1.0f);
  }
  // pass 2: scatter to sorted position (plain src)
  for (int j = beg + t; j < end; j += TB) {
    int p = ebuf[j];
    int slot = atomicAdd(&cur[p >> 17], 1);
    ebuf2[slot] = p & 0x1FFFF;
  }
}

// hs = (X @ W1) * disq[row], written as two half-tables [N][8] (3.2 MB each).
__global__ void k_gemm1(const float* __restrict__ x, const float* __restrict__ W,
                        const float* __restrict__ disq,
                        float* __restrict__ hlo, float* __restrict__ hhi) {
  int r = blockIdx.x * blockDim.x + threadIdx.x;
  if (r >= N_NODES) return;
  const float4* xr = (const float4*)(x + (size_t)r * IN_CH);
  float acc[H];
#pragma unroll
  for (int c = 0; c < H; c++) acc[c] = 0.f;
  for (int k4 = 0; k4 < IN_CH / 4; k4++) {
    float4 xv = xr[k4];
    const float* wr = W + k4 * 4 * H;
    float xs[4] = {xv.x, xv.y, xv.z, xv.w};
#pragma unroll
    for (int j = 0; j < 4; j++) {
#pragma unroll
      for (int c = 0; c < H; c++) acc[c] = fmaf(xs[j], wr[j * H + c], acc[c]);
    }
  }
  float dn = disq[r];
  float4* lo = (float4*)(hlo + (size_t)r * 8);
  float4* hi = (float4*)(hhi + (size_t)r * 8);
  lo[0] = make_float4(acc[0] * dn, acc[1] * dn, acc[2] * dn, acc[3] * dn);
  lo[1] = make_float4(acc[4] * dn, acc[5] * dn, acc[6] * dn, acc[7] * dn);
  hi[0] = make_float4(acc[8] * dn, acc[9] * dn, acc[10] * dn, acc[11] * dn);
  hi[1] = make_float4(acc[12] * dn, acc[13] * dn, acc[14] * dn, acc[15] * dn);
}

// CSR gather, half-channel: grid (NB, 2). 8 lanes per node (lane=channel),
// 2 nodes per 8-lane group, register accumulation — zero atomics.
// agg[n][half*8+c] = dn*(sum_e hs[src][c] + hs[n][c]) + b[half*8+c]
__global__ void k_gath8(const int* __restrict__ nrs, const int* __restrict__ ebuf2,
                        const float* __restrict__ disq,
                        const float* __restrict__ hlo, const float* __restrict__ hhi,
                        const float* __restrict__ bias, float* __restrict__ agg) {
  int b = blockIdx.x, half = blockIdx.y, t = threadIdx.x;
  const float* hs = half ? hhi : hlo;
  int grp = t >> 3, lane = t & 7;  // 32 groups of 8 lanes
#pragma unroll
  for (int k = 0; k < 2; k++) {
    int node = b * BN + grp * 2 + k;
    if (node >= N_NODES) continue;
    int beg = nrs[node], end = nrs[node + 1];
    float acc = 0.f;
    for (int j = beg; j < end; j++) {
      int src = ebuf2[j];
      acc += hs[(size_t)src * 8 + lane];
    }
    float dn = disq[node];
    float r = fmaf(acc + hs[(size_t)node * 8 + lane], dn, bias[half * 8 + lane]);
    agg[(size_t)node * H + half * 8 + lane] = r;
  }
}

// hs = (relu(agg) @ W2) * disq, written as halves
__global__ void k_gemm16(const float* __restrict__ agg, const float* __restrict__ W,
                         const float* __restrict__ disq,
                         float* __restrict__ hlo, float* __restrict__ hhi) {
  int r = blockIdx.x * blockDim.x + threadIdx.x;
  if (r >= N_NODES) return;
  const float4* ap = (const float4*)(agg + (size_t)r * H);
  float v[H];
#pragma unroll
  for (int q = 0; q < 4; q++) {
    float4 t = ap[q];
    v[4 * q + 0] = fmaxf(t.x, 0.f);
    v[4 * q + 1] = fmaxf(t.y, 0.f);
    v[4 * q + 2] = fmaxf(t.z, 0.f);
    v[4 * q + 3] = fmaxf(t.w, 0.f);
  }
  float acc[H];
#pragma unroll
  for (int c = 0; c < H; c++) acc[c] = 0.f;
#pragma unroll
  for (int k = 0; k < H; k++) {
#pragma unroll
    for (int c = 0; c < H; c++) acc[c] = fmaf(v[k], W[k * H + c], acc[c]);
  }
  float dn = disq[r];
  float4* lo = (float4*)(hlo + (size_t)r * 8);
  float4* hi = (float4*)(hhi + (size_t)r * 8);
  lo[0] = make_float4(acc[0] * dn, acc[1] * dn, acc[2] * dn, acc[3] * dn);
  lo[1] = make_float4(acc[4] * dn, acc[5] * dn, acc[6] * dn, acc[7] * dn);
  hi[0] = make_float4(acc[8] * dn, acc[9] * dn, acc[10] * dn, acc[11] * dn);
  hi[1] = make_float4(acc[12] * dn, acc[13] * dn, acc[14] * dn, acc[15] * dn);
}

// hs3 = (relu(agg2) @ W3) * disq   (400 KB table)
__global__ void k_gemm_last(const float* __restrict__ agg, const float* __restrict__ W,
                            const float* __restrict__ disq, float* __restrict__ hs3) {
  int r = blockIdx.x * blockDim.x + threadIdx.x;
  if (r >= N_NODES) return;
  const float4* ap = (const float4*)(agg + (size_t)r * H);
  float acc = 0.f;
#pragma unroll
  for (int q = 0; q < 4; q++) {
    float4 t = ap[q];
    acc = fmaf(fmaxf(t.x, 0.f), W[4 * q + 0], acc);
    acc = fmaf(fmaxf(t.y, 0.f), W[4 * q + 1], acc);
    acc = fmaf(fmaxf(t.z, 0.f), W[4 * q + 2], acc);
    acc = fmaf(fmaxf(t.w, 0.f), W[4 * q + 3], acc);
  }
  hs3[r] = acc * disq[r];
}

// CSR gather, 1 channel: 4 lanes per node, shfl reduce.
// out[n] = dn*(sum_e hs3[src] + hs3[n]) + b3
__global__ void k_gath1(const int* __restrict__ nrs, const int* __restrict__ ebuf2,
                        const float* __restrict__ disq, const float* __restrict__ hs3,
                        const float* __restrict__ bias, float* __restrict__ out) {
  int b = blockIdx.x, t = threadIdx.x;
  int grp = t >> 2, lane = t & 3;  // 64 groups of 4 lanes
  int node = b * BN + grp;
  if (node >= N_NODES) return;
  int beg = nrs[node], end = nrs[node + 1];
  float acc = 0.f;
  for (int j = beg + lane; j < end; j += 4) acc += hs3[ebuf2[j]];
  acc += __shfl_xor(acc, 1);
  acc += __shfl_xor(acc, 2);
  if (lane == 0) {
    out[node] = fmaf(acc + hs3[node], disq[node], bias[0]);
  }
}

extern "C" void kernel_launch(void* const* d_in, const int* in_sizes, int n_in,
                              void* d_out, int out_size, void* d_ws, size_t ws_size,
                              hipStream_t stream) {
  const float* x = (const float*)d_in[0];
  const int* ei = (const int*)d_in[1];  // integer inputs delivered as int32
  const float* W1 = (const float*)d_in[2];
  const float* b1 = (const float*)d_in[3];
  const float* W2 = (const float*)d_in[4];
  const float* b2 = (const float*)d_in[5];
  const float* W3 = (const float*)d_in[6];
  const float* b3 = (const float*)d_in[7];
  float* out = (float*)d_out;

  // Workspace (~33.4 MB). agg aliases ebuf (dead after k_bsort).
  int* ebuf = (int*)d_ws;                      // E packed edges (12.8 MB)
  int* ebuf2 = ebuf + N_EDGES;                 // E sorted src (12.8 MB)
  int* cnt2 = ebuf2 + N_EDGES;                 // NSEG*NB*PAD
  int* cur2 = cnt2 + NSEG * NB * PAD;          // NSEG*NB*PAD
  int* base = cur2 + NSEG * NB * PAD;          // NB+1
  int* nrs = base + (NB + 1);                  // N+1
  float* disq = (float*)(nrs + N_NODES + 1);   // N
  float* hlo = disq + N_NODES;                 // 8N (3.2 MB)
  float* hhi = hlo + (size_t)N_NODES * 8;      // 8N (3.2 MB)
  float* agg = (float*)ebuf;                   // 16N, aliases ebuf
  float* hs3 = hlo;                            // reuse (hlo dead after layer-2 gath)

  int gN = (N_NODES + TB - 1) / TB;

  // Build bucketed, dst-sorted edge list + degrees
  int nCnt = NSEG * NB * PAD;
  k_zero<<<(nCnt + TB - 1) / TB, TB, 0, stream>>>(cnt2, nCnt);
  k_hist2<<<GSCAT, TB, 0, stream>>>(ei, cnt2);
  k_scan<<<1, TB, 0, stream>>>(cnt2, cur2, base);
  k_bscatter<<<GSCAT, TB, 0, stream>>>(ei, cur2, ebuf);
  k_bsort<<<NB, TB, 0, stream>>>(base, ebuf, ebuf2, nrs, disq);

  // Layer 1
  k_gemm1<<<gN, TB, 0, stream>>>(x, W1, disq, hlo, hhi);
  k_gath8<<<dim3(NB, 2), TB, 0, stream>>>(nrs, ebuf2, disq, hlo, hhi, b1, agg);
  // Layer 2
  k_gemm16<<<gN, TB, 0, stream>>>(agg, W2, disq, hlo, hhi);
  k_gath8<<<dim3(NB, 2), TB, 0, stream>>>(nrs, ebuf2, disq, hlo, hhi, b2, agg);
  // Layer 3
  k_gemm_last<<<gN, TB, 0, stream>>>(agg, W3, disq, hs3);
  k_gath1<<<NB, TB, 0, stream>>>(nrs, ebuf2, disq, hs3, b3, out);
}

// Round 7
// 672.001 us; speedup vs baseline: 1.9422x; 1.3011x over previous
//
#include <hip/hip_runtime.h>
#include <hip/hip_bf16.h>

static constexpr int N_NODES = 100000;
static constexpr int N_EDGES = 3200000;
static constexpr int IN_CH = 512;
static constexpr int H = 16;
static constexpr int TB = 256;

static constexpr int BN = 256;                       // nodes per bucket
static constexpr int NB = (N_NODES + BN - 1) / BN;   // 391 buckets
static constexpr int CAP = 8960;                     // slots per bucket (mean 8192, +8.5 sigma)
static constexpr int CHUNK = 8192;                   // edges per scatter WG
static constexpr int GRID_SC = (N_EDGES + CHUNK - 1) / CHUNK;  // 391
static constexpr int NBLK64 = (N_NODES + 63) / 64;   // 1563 (gather grids)

// gcur[b] = b*CAP  (bump cursors into fixed-capacity bucket regions)
__global__ void k_init(int* __restrict__ gcur) {
  int b = blockIdx.x * blockDim.x + threadIdx.x;
  if (b < NB) gcur[b] = b * CAP;
}

// Chunked reserve-then-write scatter. Each WG: count its chunk per bucket in
// LDS, reserve one contiguous run per bucket via a single global atomic, then
// write the run contiguously (lines written by one WG within ~us -> L2 merges).
// pack = (dst&255)<<17 | src  (src < 2^17)
__global__ void k_cscatter(const int* __restrict__ ei, int* __restrict__ gcur,
                           int* __restrict__ ebuf) {
  __shared__ int cnt[NB];
  __shared__ int gofs[NB];
  int t = threadIdx.x;
  int c0 = blockIdx.x * CHUNK;
  int c1 = min(c0 + CHUNK, N_EDGES);
  for (int b = t; b < NB; b += TB) cnt[b] = 0;
  __syncthreads();
  for (int j = c0 + t; j < c1; j += TB) atomicAdd(&cnt[ei[N_EDGES + j] >> 8], 1);
  __syncthreads();
  for (int b = t; b < NB; b += TB)
    if (cnt[b] > 0) gofs[b] = atomicAdd(&gcur[b], cnt[b]);
  __syncthreads();
  for (int j = c0 + t; j < c1; j += TB) {
    int s = ei[j];
    int d = ei[N_EDGES + j];
    int slot = atomicAdd(&gofs[d >> 8], 1);
    ebuf[slot] = ((d & 255) << 17) | s;
  }
}

// Compact bucket bases: bbase[b] = prefix of (gcur[b]-b*CAP). Single WG.
__global__ void k_bscan(const int* __restrict__ gcur, int* __restrict__ bbase) {
  __shared__ int c[512];
  __shared__ int s[TB];
  int t = threadIdx.x;
  c[t] = (t < NB) ? gcur[t] - t * CAP : 0;
  int u = t + 256;
  c[u] = (u < NB) ? gcur[u] - u * CAP : 0;
  __syncthreads();
  s[t] = c[2 * t] + c[2 * t + 1];
  __syncthreads();
  for (int off = 1; off < TB; off <<= 1) {
    int v = (t >= off) ? s[t - off] : 0;
    __syncthreads();
    s[t] += v;
    __syncthreads();
  }
  int e = (t == 0) ? 0 : s[t - 1];
  if (2 * t < NB) bbase[2 * t] = e;
  if (2 * t + 1 < NB) bbase[2 * t + 1] = e + c[2 * t];
}

// Per-bucket counting sort: ebuf (packed, bucket region) -> ebuf2 (plain src,
// compacted, grouped by node). Emits nrs[] (incl. sentinel nrs[N]=E) and disq.
__global__ void k_bsort(const int* __restrict__ gcur, const int* __restrict__ bbase,
                        const int* __restrict__ ebuf, int* __restrict__ ebuf2,
                        int* __restrict__ nrs, float* __restrict__ disq) {
  __shared__ int cnt[BN];
  __shared__ int pre[BN];
  __shared__ int cur[BN];
  int b = blockIdx.x, t = threadIdx.x;
  cnt[t] = 0;
  __syncthreads();
  int beg = b * CAP, end = gcur[b];
  for (int j = beg + t; j < end; j += TB) atomicAdd(&cnt[ebuf[j] >> 17], 1);
  __syncthreads();
  pre[t] = cnt[t];
  __syncthreads();
  for (int off = 1; off < TB; off <<= 1) {
    int v = (t >= off) ? pre[t - off] : 0;
    __syncthreads();
    pre[t] += v;
    __syncthreads();
  }
  int start = bbase[b] + ((t == 0) ? 0 : pre[t - 1]);
  cur[t] = start;
  int node = b * BN + t;
  if (node <= N_NODES) nrs[node] = start;
  if (node < N_NODES) disq[node] = 1.0f / sqrtf((float)cnt[t] + 1.0f);
  __syncthreads();
  for (int j = beg + t; j < end; j += TB) {
    int p = ebuf[j];
    int slot = atomicAdd(&cur[p >> 17], 1);
    ebuf2[slot] = p & 0x1FFFF;
  }
}

// hs = (X @ W1) * disq[row], written as two half-tables [N][8] (3.2 MB each).
__global__ void k_gemm1(const float* __restrict__ x, const float* __restrict__ W,
                        const float* __restrict__ disq,
                        float* __restrict__ hlo, float* __restrict__ hhi) {
  int r = blockIdx.x * blockDim.x + threadIdx.x;
  if (r >= N_NODES) return;
  const float4* xr = (const float4*)(x + (size_t)r * IN_CH);
  float acc[H];
#pragma unroll
  for (int c = 0; c < H; c++) acc[c] = 0.f;
  for (int k4 = 0; k4 < IN_CH / 4; k4++) {
    float4 xv = xr[k4];
    const float* wr = W + k4 * 4 * H;
    float xs[4] = {xv.x, xv.y, xv.z, xv.w};
#pragma unroll
    for (int j = 0; j < 4; j++) {
#pragma unroll
      for (int c = 0; c < H; c++) acc[c] = fmaf(xs[j], wr[j * H + c], acc[c]);
    }
  }
  float dn = disq[r];
  float4* lo = (float4*)(hlo + (size_t)r * 8);
  float4* hi = (float4*)(hhi + (size_t)r * 8);
  lo[0] = make_float4(acc[0] * dn, acc[1] * dn, acc[2] * dn, acc[3] * dn);
  lo[1] = make_float4(acc[4] * dn, acc[5] * dn, acc[6] * dn, acc[7] * dn);
  hi[0] = make_float4(acc[8] * dn, acc[9] * dn, acc[10] * dn, acc[11] * dn);
  hi[1] = make_float4(acc[12] * dn, acc[13] * dn, acc[14] * dn, acc[15] * dn);
}

// CSR gather, half-channel: grid (NBLK64, 2). 8 lanes per node (lane=channel),
// 2 nodes per 8-lane group, register accumulation — zero atomics.
__global__ void k_gath8(const int* __restrict__ nrs, const int* __restrict__ ebuf2,
                        const float* __restrict__ disq,
                        const float* __restrict__ hlo, const float* __restrict__ hhi,
                        const float* __restrict__ bias, float* __restrict__ agg) {
  int b = blockIdx.x, half = blockIdx.y, t = threadIdx.x;
  const float* hs = half ? hhi : hlo;
  int grp = t >> 3, lane = t & 7;  // 32 groups of 8 lanes
#pragma unroll
  for (int k = 0; k < 2; k++) {
    int node = b * 64 + grp * 2 + k;
    if (node >= N_NODES) continue;
    int beg = nrs[node], end = nrs[node + 1];
    float acc = 0.f;
    for (int j = beg; j < end; j++) {
      int src = ebuf2[j];
      acc += hs[(size_t)src * 8 + lane];
    }
    float dn = disq[node];
    float r = fmaf(acc + hs[(size_t)node * 8 + lane], dn, bias[half * 8 + lane]);
    agg[(size_t)node * H + half * 8 + lane] = r;
  }
}

// hs = (relu(agg) @ W2) * disq, written as halves
__global__ void k_gemm16(const float* __restrict__ agg, const float* __restrict__ W,
                         const float* __restrict__ disq,
                         float* __restrict__ hlo, float* __restrict__ hhi) {
  int r = blockIdx.x * blockDim.x + threadIdx.x;
  if (r >= N_NODES) return;
  const float4* ap = (const float4*)(agg + (size_t)r * H);
  float v[H];
#pragma unroll
  for (int q = 0; q < 4; q++) {
    float4 t = ap[q];
    v[4 * q + 0] = fmaxf(t.x, 0.f);
    v[4 * q + 1] = fmaxf(t.y, 0.f);
    v[4 * q + 2] = fmaxf(t.z, 0.f);
    v[4 * q + 3] = fmaxf(t.w, 0.f);
  }
  float acc[H];
#pragma unroll
  for (int c = 0; c < H; c++) acc[c] = 0.f;
#pragma unroll
  for (int k = 0; k < H; k++) {
#pragma unroll
    for (int c = 0; c < H; c++) acc[c] = fmaf(v[k], W[k * H + c], acc[c]);
  }
  float dn = disq[r];
  float4* lo = (float4*)(hlo + (size_t)r * 8);
  float4* hi = (float4*)(hhi + (size_t)r * 8);
  lo[0] = make_float4(acc[0] * dn, acc[1] * dn, acc[2] * dn, acc[3] * dn);
  lo[1] = make_float4(acc[4] * dn, acc[5] * dn, acc[6] * dn, acc[7] * dn);
  hi[0] = make_float4(acc[8] * dn, acc[9] * dn, acc[10] * dn, acc[11] * dn);
  hi[1] = make_float4(acc[12] * dn, acc[13] * dn, acc[14] * dn, acc[15] * dn);
}

// hs3 = (relu(agg2) @ W3) * disq   (400 KB table)
__global__ void k_gemm_last(const float* __restrict__ agg, const float* __restrict__ W,
                            const float* __restrict__ disq, float* __restrict__ hs3) {
  int r = blockIdx.x * blockDim.x + threadIdx.x;
  if (r >= N_NODES) return;
  const float4* ap = (const float4*)(agg + (size_t)r * H);
  float acc = 0.f;
#pragma unroll
  for (int q = 0; q < 4; q++) {
    float4 t = ap[q];
    acc = fmaf(fmaxf(t.x, 0.f), W[4 * q + 0], acc);
    acc = fmaf(fmaxf(t.y, 0.f), W[4 * q + 1], acc);
    acc = fmaf(fmaxf(t.z, 0.f), W[4 * q + 2], acc);
    acc = fmaf(fmaxf(t.w, 0.f), W[4 * q + 3], acc);
  }
  hs3[r] = acc * disq[r];
}

// CSR gather, 1 channel: 4 lanes per node, shfl reduce.
__global__ void k_gath1(const int* __restrict__ nrs, const int* __restrict__ ebuf2,
                        const float* __restrict__ disq, const float* __restrict__ hs3,
                        const float* __restrict__ bias, float* __restrict__ out) {
  int b = blockIdx.x, t = threadIdx.x;
  int grp = t >> 2, lane = t & 3;  // 64 groups of 4 lanes
  int node = b * 64 + grp;
  if (node >= N_NODES) return;
  int beg = nrs[node], end = nrs[node + 1];
  float acc = 0.f;
  for (int j = beg + lane; j < end; j += 4) acc += hs3[ebuf2[j]];
  acc += __shfl_xor(acc, 1);
  acc += __shfl_xor(acc, 2);
  if (lane == 0) {
    out[node] = fmaf(acc + hs3[node], disq[node], bias[0]);
  }
}

extern "C" void kernel_launch(void* const* d_in, const int* in_sizes, int n_in,
                              void* d_out, int out_size, void* d_ws, size_t ws_size,
                              hipStream_t stream) {
  const float* x = (const float*)d_in[0];
  const int* ei = (const int*)d_in[1];  // integer inputs delivered as int32
  const float* W1 = (const float*)d_in[2];
  const float* b1 = (const float*)d_in[3];
  const float* W2 = (const float*)d_in[4];
  const float* b2 = (const float*)d_in[5];
  const float* W3 = (const float*)d_in[6];
  const float* b3 = (const float*)d_in[7];
  float* out = (float*)d_out;

  // Workspace (~33.9 MB). agg aliases ebuf (dead after k_bsort).
  int* ebuf = (int*)d_ws;                      // NB*CAP packed edges (14.0 MB)
  int* ebuf2 = ebuf + (size_t)NB * CAP;        // E sorted src, compacted (12.8 MB)
  int* gcur = ebuf2 + N_EDGES;                 // NB
  int* bbase = gcur + NB;                      // NB
  int* nrs = bbase + NB;                       // N+1
  float* disq = (float*)(nrs + N_NODES + 1);   // N
  float* hlo = disq + N_NODES;                 // 8N (3.2 MB)
  float* hhi = hlo + (size_t)N_NODES * 8;      // 8N (3.2 MB)
  float* agg = (float*)ebuf;                   // 16N, aliases ebuf
  float* hs3 = hlo;                            // reuse (hlo dead after layer-2 gath)

  int gN = (N_NODES + TB - 1) / TB;

  // Build bucketed, dst-sorted edge list + degrees (no global hist/scan needed)
  k_init<<<(NB + TB - 1) / TB, TB, 0, stream>>>(gcur);
  k_cscatter<<<GRID_SC, TB, 0, stream>>>(ei, gcur, ebuf);
  k_bscan<<<1, TB, 0, stream>>>(gcur, bbase);
  k_bsort<<<NB, TB, 0, stream>>>(gcur, bbase, ebuf, ebuf2, nrs, disq);

  // Layer 1
  k_gemm1<<<gN, TB, 0, stream>>>(x, W1, disq, hlo, hhi);
  k_gath8<<<dim3(NBLK64, 2), TB, 0, stream>>>(nrs, ebuf2, disq, hlo, hhi, b1, agg);
  // Layer 2
  k_gemm16<<<gN, TB, 0, stream>>>(agg, W2, disq, hlo, hhi);
  k_gath8<<<dim3(NBLK64, 2), TB, 0, stream>>>(nrs, ebuf2, disq, hlo, hhi, b2, agg);
  // Layer 3
  k_gemm_last<<<gN, TB, 0, stream>>>(agg, W3, disq, hs3);
  k_gath1<<<NBLK64, TB, 0, stream>>>(nrs, ebuf2, disq, hs3, b3, out);
}

// Round 8
// 552.438 us; speedup vs baseline: 2.3625x; 1.2164x over previous
//
#include <hip/hip_runtime.h>
#include <hip/hip_bf16.h>

static constexpr int N_NODES = 100000;
static constexpr int N_EDGES = 3200000;
static constexpr int IN_CH = 512;
static constexpr int H = 16;
static constexpr int TB = 256;

static constexpr int BN = 256;                       // nodes per bucket
static constexpr int NB = (N_NODES + BN - 1) / BN;   // 391 buckets
static constexpr int CAP = 8960;                     // ebuf slots/bucket (mean 8192, +8.5 sigma)
static constexpr int CAP2 = CAP + 3 * BN;            // 9728: sorted+padded slots (mult of 4)
static constexpr int CHUNK = 8192;                   // edges per scatter WG
static constexpr int GRID_SC = (N_EDGES + CHUNK - 1) / CHUNK;  // 391
static constexpr int NBLK64 = (N_NODES + 63) / 64;   // 1563 (gather grids)

// gcur[b] = b*CAP  (bump cursors into fixed-capacity bucket regions)
__global__ void k_init(int* __restrict__ gcur) {
  int b = blockIdx.x * blockDim.x + threadIdx.x;
  if (b < NB) gcur[b] = b * CAP;
}

// Chunked reserve-then-write scatter (one contiguous run per (WG,bucket)).
// pack = (dst&255)<<17 | src  (src < 2^17)
__global__ void k_cscatter(const int* __restrict__ ei, int* __restrict__ gcur,
                           int* __restrict__ ebuf) {
  __shared__ int cnt[NB];
  __shared__ int gofs[NB];
  int t = threadIdx.x;
  int c0 = blockIdx.x * CHUNK;
  int c1 = min(c0 + CHUNK, N_EDGES);
  for (int b = t; b < NB; b += TB) cnt[b] = 0;
  __syncthreads();
  for (int j = c0 + t; j < c1; j += TB) atomicAdd(&cnt[ei[N_EDGES + j] >> 8], 1);
  __syncthreads();
  for (int b = t; b < NB; b += TB)
    if (cnt[b] > 0) gofs[b] = atomicAdd(&gcur[b], cnt[b]);
  __syncthreads();
  for (int j = c0 + t; j < c1; j += TB) {
    int s = ei[j];
    int d = ei[N_EDGES + j];
    int slot = atomicAdd(&gofs[d >> 8], 1);
    ebuf[slot] = ((d & 255) << 17) | s;
  }
}

// Per-bucket counting sort with 4-slot-aligned per-node runs; pads point at
// dummy node N_NODES (hs[N]=0). Emits nrs/nend (padded end) and disq.
__global__ void k_bsort(const int* __restrict__ gcur, const int* __restrict__ ebuf,
                        int* __restrict__ ebuf2, int* __restrict__ nrs,
                        int* __restrict__ nend, float* __restrict__ disq) {
  __shared__ int cnt[BN];
  __shared__ int pre[BN];
  __shared__ int cur[BN];
  int b = blockIdx.x, t = threadIdx.x;
  cnt[t] = 0;
  __syncthreads();
  int beg = b * CAP, end = gcur[b];
  for (int j = beg + t; j < end; j += TB) atomicAdd(&cnt[ebuf[j] >> 17], 1);
  __syncthreads();
  int myc = cnt[t];
  int ac = (myc + 3) & ~3;
  pre[t] = ac;
  __syncthreads();
  for (int off = 1; off < TB; off <<= 1) {
    int v = (t >= off) ? pre[t - off] : 0;
    __syncthreads();
    pre[t] += v;
    __syncthreads();
  }
  int start = b * CAP2 + ((t == 0) ? 0 : pre[t - 1]);
  cur[t] = start;
  int node = b * BN + t;
  if (node < N_NODES) {
    nrs[node] = start;
    nend[node] = start + ac;
    disq[node] = 1.0f / sqrtf((float)myc + 1.0f);
    for (int j = start + myc; j < start + ac; j++) ebuf2[j] = N_NODES;  // dummy pads
  }
  __syncthreads();
  for (int j = beg + t; j < end; j += TB) {
    int p = ebuf[j];
    int slot = atomicAdd(&cur[p >> 17], 1);
    ebuf2[slot] = p & 0x1FFFF;
  }
}

// hs = (X @ W1) * disq[row] as half-tables [N+1][8]; row N (dummy) = zeros in
// all four tables + hs3. TB=64 for smoother CU balance (1564 WGs).
__global__ void k_gemm1(const float* __restrict__ x, const float* __restrict__ W,
                        const float* __restrict__ disq,
                        float* __restrict__ hloA, float* __restrict__ hhiA,
                        float* __restrict__ hloB, float* __restrict__ hhiB,
                        float* __restrict__ hs3) {
  int r = blockIdx.x * blockDim.x + threadIdx.x;
  if (r > N_NODES) return;
  if (r == N_NODES) {  // dummy rows for gather pads
    float4 z = make_float4(0.f, 0.f, 0.f, 0.f);
    ((float4*)(hloA + (size_t)r * 8))[0] = z;
    ((float4*)(hloA + (size_t)r * 8))[1] = z;
    ((float4*)(hhiA + (size_t)r * 8))[0] = z;
    ((float4*)(hhiA + (size_t)r * 8))[1] = z;
    ((float4*)(hloB + (size_t)r * 8))[0] = z;
    ((float4*)(hloB + (size_t)r * 8))[1] = z;
    ((float4*)(hhiB + (size_t)r * 8))[0] = z;
    ((float4*)(hhiB + (size_t)r * 8))[1] = z;
    hs3[r] = 0.f;
    return;
  }
  const float4* xr = (const float4*)(x + (size_t)r * IN_CH);
  float acc[H];
#pragma unroll
  for (int c = 0; c < H; c++) acc[c] = 0.f;
  for (int k4 = 0; k4 < IN_CH / 4; k4++) {
    float4 xv = xr[k4];
    const float* wr = W + k4 * 4 * H;
    float xs[4] = {xv.x, xv.y, xv.z, xv.w};
#pragma unroll
    for (int j = 0; j < 4; j++) {
#pragma unroll
      for (int c = 0; c < H; c++) acc[c] = fmaf(xs[j], wr[j * H + c], acc[c]);
    }
  }
  float dn = disq[r];
  float4* lo = (float4*)(hloA + (size_t)r * 8);
  float4* hi = (float4*)(hhiA + (size_t)r * 8);
  lo[0] = make_float4(acc[0] * dn, acc[1] * dn, acc[2] * dn, acc[3] * dn);
  lo[1] = make_float4(acc[4] * dn, acc[5] * dn, acc[6] * dn, acc[7] * dn);
  hi[0] = make_float4(acc[8] * dn, acc[9] * dn, acc[10] * dn, acc[11] * dn);
  hi[1] = make_float4(acc[12] * dn, acc[13] * dn, acc[14] * dn, acc[15] * dn);
}

// Fused gather (both halves, 4x-unrolled int4 index loads) + relu + 16x16 GEMM
// + disq scale. One WG per 64 nodes. out = (relu(agg)@W2)*dn, agg in LDS.
__global__ void k_gath_mid(const int* __restrict__ nrs, const int* __restrict__ nend,
                           const int* __restrict__ ebuf2, const float* __restrict__ disq,
                           const float* __restrict__ inlo, const float* __restrict__ inhi,
                           const float* __restrict__ W2, const float* __restrict__ bias,
                           float* __restrict__ outlo, float* __restrict__ outhi) {
  __shared__ float agg[64 * 16];
  __shared__ float w[256];
  int b = blockIdx.x, t = threadIdx.x;
  w[t] = W2[t];
  int grp = t >> 3, lane = t & 7;  // 32 groups of 8 lanes
#pragma unroll
  for (int ph = 0; ph < 2; ph++) {
    const float* hs = ph ? inhi : inlo;
#pragma unroll
    for (int k = 0; k < 2; k++) {
      int node = b * 64 + grp * 2 + k;
      if (node < N_NODES) {
        int beg = nrs[node], endp = nend[node];
        float acc = 0.f;
        for (int j = beg; j < endp; j += 4) {
          int4 s = *(const int4*)(ebuf2 + j);
          float a0 = hs[(size_t)s.x * 8 + lane];
          float a1 = hs[(size_t)s.y * 8 + lane];
          float a2 = hs[(size_t)s.z * 8 + lane];
          float a3 = hs[(size_t)s.w * 8 + lane];
          acc += (a0 + a1) + (a2 + a3);
        }
        float dn = disq[node];
        agg[(grp * 2 + k) * 16 + ph * 8 + lane] =
            fmaf(acc + hs[(size_t)node * 8 + lane], dn, bias[ph * 8 + lane]);
      }
    }
  }
  __syncthreads();
  int nl = t >> 2, q = t & 3;
  int node = b * 64 + nl;
  if (node < N_NODES) {
    float o0 = 0.f, o1 = 0.f, o2 = 0.f, o3 = 0.f;
#pragma unroll
    for (int c4 = 0; c4 < 4; c4++) {
      float4 av = *(const float4*)(agg + nl * 16 + c4 * 4);
      float vs[4] = {av.x, av.y, av.z, av.w};
#pragma unroll
      for (int i2 = 0; i2 < 4; i2++) {
        float v = fmaxf(vs[i2], 0.f);
        const float* wr = w + (c4 * 4 + i2) * 16 + q * 4;
        o0 = fmaf(v, wr[0], o0);
        o1 = fmaf(v, wr[1], o1);
        o2 = fmaf(v, wr[2], o2);
        o3 = fmaf(v, wr[3], o3);
      }
    }
    float dn = disq[node];
    float4 r = make_float4(o0 * dn, o1 * dn, o2 * dn, o3 * dn);
    if (q < 2) *(float4*)(outlo + (size_t)node * 8 + q * 4) = r;
    else *(float4*)(outhi + (size_t)node * 8 + (q - 2) * 4) = r;
  }
}

// Fused gather + relu + 16x1 GEMM + disq scale -> hs3.
__global__ void k_gath_last(const int* __restrict__ nrs, const int* __restrict__ nend,
                            const int* __restrict__ ebuf2, const float* __restrict__ disq,
                            const float* __restrict__ inlo, const float* __restrict__ inhi,
                            const float* __restrict__ W3, const float* __restrict__ bias,
                            float* __restrict__ hs3) {
  __shared__ float agg[64 * 16];
  __shared__ float w3[16];
  int b = blockIdx.x, t = threadIdx.x;
  if (t < 16) w3[t] = W3[t];
  int grp = t >> 3, lane = t & 7;
#pragma unroll
  for (int ph = 0; ph < 2; ph++) {
    const float* hs = ph ? inhi : inlo;
#pragma unroll
    for (int k = 0; k < 2; k++) {
      int node = b * 64 + grp * 2 + k;
      if (node < N_NODES) {
        int beg = nrs[node], endp = nend[node];
        float acc = 0.f;
        for (int j = beg; j < endp; j += 4) {
          int4 s = *(const int4*)(ebuf2 + j);
          float a0 = hs[(size_t)s.x * 8 + lane];
          float a1 = hs[(size_t)s.y * 8 + lane];
          float a2 = hs[(size_t)s.z * 8 + lane];
          float a3 = hs[(size_t)s.w * 8 + lane];
          acc += (a0 + a1) + (a2 + a3);
        }
        float dn = disq[node];
        agg[(grp * 2 + k) * 16 + ph * 8 + lane] =
            fmaf(acc + hs[(size_t)node * 8 + lane], dn, bias[ph * 8 + lane]);
      }
    }
  }
  __syncthreads();
  int nl = t >> 2, q = t & 3;
  int node = b * 64 + nl;
  if (node < N_NODES) {
    float4 av = *(const float4*)(agg + nl * 16 + q * 4);
    float o = fmaxf(av.x, 0.f) * w3[q * 4 + 0];
    o = fmaf(fmaxf(av.y, 0.f), w3[q * 4 + 1], o);
    o = fmaf(fmaxf(av.z, 0.f), w3[q * 4 + 2], o);
    o = fmaf(fmaxf(av.w, 0.f), w3[q * 4 + 3], o);
    o += __shfl_xor(o, 1);
    o += __shfl_xor(o, 2);
    if (q == 0) hs3[node] = o * disq[node];
  }
}

// Final 1-channel gather: 4 lanes/node, int4 index loads, shfl reduce.
__global__ void k_gath1(const int* __restrict__ nrs, const int* __restrict__ nend,
                        const int* __restrict__ ebuf2, const float* __restrict__ disq,
                        const float* __restrict__ hs3, const float* __restrict__ bias,
                        float* __restrict__ out) {
  int b = blockIdx.x, t = threadIdx.x;
  int nl = t >> 2, lane = t & 3;
  int node = b * 64 + nl;
  if (node >= N_NODES) return;
  int beg = nrs[node], endp = nend[node];
  float acc = 0.f;
  for (int j = beg + 4 * lane; j < endp; j += 16) {
    int4 s = *(const int4*)(ebuf2 + j);
    acc += (hs3[s.x] + hs3[s.y]) + (hs3[s.z] + hs3[s.w]);
  }
  acc += __shfl_xor(acc, 1);
  acc += __shfl_xor(acc, 2);
  if (lane == 0) out[node] = fmaf(acc + hs3[node], disq[node], bias[0]);
}

extern "C" void kernel_launch(void* const* d_in, const int* in_sizes, int n_in,
                              void* d_out, int out_size, void* d_ws, size_t ws_size,
                              hipStream_t stream) {
  const float* x = (const float*)d_in[0];
  const int* ei = (const int*)d_in[1];  // integer inputs delivered as int32
  const float* W1 = (const float*)d_in[2];
  const float* b1 = (const float*)d_in[3];
  const float* W2 = (const float*)d_in[4];
  const float* b2 = (const float*)d_in[5];
  const float* W3 = (const float*)d_in[6];
  const float* b3 = (const float*)d_in[7];
  float* out = (float*)d_out;

  // Workspace (~44 MB), 16B-aligned segments.
  int* ebuf = (int*)d_ws;                        // NB*CAP (14.0 MB)
  int* ebuf2 = ebuf + (size_t)NB * CAP;          // NB*CAP2 (15.2 MB), %4==0 offset
  int* gcur = ebuf2 + (size_t)NB * CAP2;         // NB
  int* nrs = gcur + NB;                          // N
  int* nend = nrs + N_NODES;                     // N
  int pad = (4 - ((NB + 2 * N_NODES) & 3)) & 3;  // realign to 16B
  float* disq = (float*)(nend + N_NODES + pad);  // N
  float* hloA = disq + N_NODES;                  // 8(N+1)
  float* hhiA = hloA + (size_t)(N_NODES + 1) * 8;
  float* hloB = hhiA + (size_t)(N_NODES + 1) * 8;
  float* hhiB = hloB + (size_t)(N_NODES + 1) * 8;
  float* hs3 = hhiB + (size_t)(N_NODES + 1) * 8;  // N+1

  k_init<<<(NB + 63) / 64, 64, 0, stream>>>(gcur);
  k_cscatter<<<GRID_SC, TB, 0, stream>>>(ei, gcur, ebuf);
  k_bsort<<<NB, TB, 0, stream>>>(gcur, ebuf, ebuf2, nrs, nend, disq);

  // Layer 1 dense part (+ dummy rows)
  k_gemm1<<<(N_NODES + 64) / 64, 64, 0, stream>>>(x, W1, disq, hloA, hhiA, hloB, hhiB, hs3);
  // Layer 1 aggregation fused with layer-2 dense 16x16
  k_gath_mid<<<NBLK64, TB, 0, stream>>>(nrs, nend, ebuf2, disq, hloA, hhiA, W2, b1, hloB, hhiB);
  // Layer 2 aggregation fused with layer-3 dense 16x1
  k_gath_last<<<NBLK64, TB, 0, stream>>>(nrs, nend, ebuf2, disq, hloB, hhiB, W3, b2, hs3);
  // Layer 3 aggregation
  k_gath1<<<NBLK64, TB, 0, stream>>>(nrs, nend, ebuf2, disq, hs3, b3, out);
}